// Round 1
// baseline (583.171 us; speedup 1.0000x reference)
//
#include <hip/hip_runtime.h>

#define EMBED 2560
#define HEADS 8
#define HDIM  320
#define BATCH 2
#define SEQ   2048
#define MTOT  (BATCH*SEQ)   // 4096
#define FTOT  (3*EMBED)     // 7680

using bf = __bf16;
typedef __bf16 bf16x8 __attribute__((ext_vector_type(8)));
typedef float  f32x4  __attribute__((ext_vector_type(4)));
typedef short  s16x8  __attribute__((ext_vector_type(8)));
typedef float  f32x4v __attribute__((ext_vector_type(4)));

__device__ __forceinline__ void gl_lds16(const bf* g, bf* l) {
    __builtin_amdgcn_global_load_lds(
        (const __attribute__((address_space(1))) void*)g,
        (__attribute__((address_space(3))) void*)l,
        16, 0, 0);
}

// ---------------- fp32 -> bf16 convert ----------------
__global__ void cvt_bf16(const float* __restrict__ in, bf* __restrict__ out, int n) {
    int i = (blockIdx.x*blockDim.x + threadIdx.x)*8;
    if (i >= n) return;
    f32x4v a = *reinterpret_cast<const f32x4v*>(in + i);
    f32x4v b = *reinterpret_cast<const f32x4v*>(in + i + 4);
    bf16x8 r;
    r[0]=(bf)a[0]; r[1]=(bf)a[1]; r[2]=(bf)a[2]; r[3]=(bf)a[3];
    r[4]=(bf)b[0]; r[5]=(bf)b[1]; r[6]=(bf)b[2]; r[7]=(bf)b[3];
    *reinterpret_cast<bf16x8*>(out + i) = r;
}

// ---------------- NT GEMM: C[M,N] = A[M,K] @ B[N,K]^T + bias ----------------
// m97 structure: 128x128 tile, BK=32, 4 waves (2x2 of 64x64), 16x16x32 bf16 MFMA.
template<bool OUTBF>
__global__ void gemm_bt(const bf* __restrict__ A, const bf* __restrict__ B,
                        const float* __restrict__ bias, void* __restrict__ Cp,
                        int M, int N, int K) {
    __shared__ bf As[128*32];
    __shared__ bf Bs[128*32];
    const int tid = threadIdx.x, lane = tid & 63, wid = tid >> 6;
    const int wr = wid >> 1, wc = wid & 1;
    const int m0 = blockIdx.y*128, n0 = blockIdx.x*128;
    const int l15 = lane & 15, l4 = lane >> 4;
    f32x4 acc[4][4] = {};

    for (int k0 = 0; k0 < K; k0 += 32) {
        #pragma unroll
        for (int j = 0; j < 2; ++j) {
            int ch  = wid*128 + j*64 + lane;      // 16B chunk index (512 per tile)
            int row = ch >> 2, col = (ch & 3)*8;  // [128 rows][4 chunks of 8 bf16]
            gl_lds16(A + (size_t)(m0 + row)*K + k0 + col, As + (wid*128 + j*64)*8);
            gl_lds16(B + (size_t)(n0 + row)*K + k0 + col, Bs + (wid*128 + j*64)*8);
        }
        __syncthreads();
        bf16x8 af[4], bfr[4];
        #pragma unroll
        for (int m = 0; m < 4; ++m)
            af[m] = *reinterpret_cast<const bf16x8*>(&As[(wr*64 + m*16 + l15)*32 + l4*8]);
        #pragma unroll
        for (int n = 0; n < 4; ++n)
            bfr[n] = *reinterpret_cast<const bf16x8*>(&Bs[(wc*64 + n*16 + l15)*32 + l4*8]);
        #pragma unroll
        for (int m = 0; m < 4; ++m)
            #pragma unroll
            for (int n = 0; n < 4; ++n)
                acc[m][n] = __builtin_amdgcn_mfma_f32_16x16x32_bf16(af[m], bfr[n], acc[m][n], 0, 0, 0);
        __syncthreads();
    }
    // epilogue: C row=(lane>>4)*4+reg, col=lane&15 (m89-verified layout)
    #pragma unroll
    for (int m = 0; m < 4; ++m) {
        #pragma unroll
        for (int n = 0; n < 4; ++n) {
            int col_g = n0 + wc*64 + n*16 + l15;
            float bv = bias[col_g];
            #pragma unroll
            for (int r = 0; r < 4; ++r) {
                int row_g = m0 + wr*64 + m*16 + l4*4 + r;
                float v = acc[m][n][r] + bv;
                if (OUTBF) ((bf*)Cp)[(size_t)row_g*N + col_g] = (bf)v;
                else       ((float*)Cp)[(size_t)row_g*N + col_g] = v;
            }
        }
    }
}

// ---------------- V repack: qkv[b,s,2E + h*D + d] -> vt[bh, d, s] ----------------
__global__ void repack_vt(const bf* __restrict__ qkv, bf* __restrict__ vt) {
    __shared__ bf tile[64][72];
    const int bh = blockIdx.z, b = bh >> 3, h = bh & 7;
    const int s0 = blockIdx.x*64, d0 = blockIdx.y*64;
    const int t = threadIdx.x;
    #pragma unroll
    for (int p = 0; p < 2; ++p) {
        int sr = (t >> 3) + p*32, ck = t & 7;
        s16x8 v = *reinterpret_cast<const s16x8*>(
            qkv + ((size_t)(b*SEQ + s0 + sr))*FTOT + 2*EMBED + h*HDIM + d0 + ck*8);
        *reinterpret_cast<s16x8*>(&tile[sr][ck*8]) = v;
    }
    __syncthreads();
    #pragma unroll
    for (int p = 0; p < 2; ++p) {
        int dr = (t >> 3) + p*32, ck = t & 7;
        bf16x8 r;
        #pragma unroll
        for (int j = 0; j < 8; ++j) r[j] = tile[ck*8 + j][dr];
        *reinterpret_cast<bf16x8*>(vt + ((size_t)bh*HDIM + d0 + dr)*SEQ + s0 + ck*8) = r;
    }
}

// ---------------- flash attention ----------------
// grid (16 q-tiles, 16 bh), 512 threads = 8 waves x 16 q-rows, KV tile = 32 keys
__global__ __launch_bounds__(512, 2)
void attn_fwd(const bf* __restrict__ qkv, const bf* __restrict__ vt, bf* __restrict__ aout) {
    __shared__ bf Ks[32][328];    // 32 keys x 320 d, +8 pad (breaks 640B stride conflicts)
    __shared__ bf Vs[320][40];    // 320 d x 32 keys, +8 pad
    __shared__ bf Ps[8][16][40];  // per-wave P round-trip
    const int bh = blockIdx.y, b = bh >> 3, h = bh & 7;
    const int tid = threadIdx.x, lane = tid & 63, wid = tid >> 6;
    const int q0 = blockIdx.x*128;
    const int qw = q0 + wid*16;
    const int l15 = lane & 15, l4 = lane >> 4;
    const float scale = 0.05590169944f;  // 1/sqrt(320)

    // hoist Q fragments (16 rows x 320 d = 10 frags)
    bf16x8 qf[10];
    const bf* qbase = qkv + ((size_t)(b*SEQ + qw + l15))*FTOT + h*HDIM + l4*8;
    #pragma unroll
    for (int d = 0; d < 10; ++d) qf[d] = *reinterpret_cast<const bf16x8*>(qbase + d*32);

    f32x4 o[20] = {};
    float mrow[4], lrow[4];
    #pragma unroll
    for (int r = 0; r < 4; ++r) { mrow[r] = -1e30f; lrow[r] = 0.f; }

    for (int kt = 0; kt < SEQ/32; ++kt) {
        const int k0 = kt*32;
        __syncthreads();
        for (int ch = tid; ch < 1280; ch += 512) {
            int row = ch/40, col = ch - row*40;          // K: 32 rows x 40 chunks
            *reinterpret_cast<s16x8*>(&Ks[row][col*8]) =
                *reinterpret_cast<const s16x8*>(
                    qkv + ((size_t)(b*SEQ + k0 + row))*FTOT + EMBED + h*HDIM + col*8);
            int vrow = ch >> 2, vcol = ch & 3;           // Vt: 320 rows x 4 chunks
            *reinterpret_cast<s16x8*>(&Vs[vrow][vcol*8]) =
                *reinterpret_cast<const s16x8*>(
                    vt + ((size_t)bh*HDIM + vrow)*SEQ + k0 + vcol*8);
        }
        __syncthreads();

        // S = Q K^T  (scores[16q][32keys], C layout: row=l4*4+r, col=l15)
        f32x4 sc[2] = {};
        #pragma unroll
        for (int kb = 0; kb < 2; ++kb)
            #pragma unroll
            for (int d = 0; d < 10; ++d) {
                bf16x8 kf = *reinterpret_cast<const bf16x8*>(&Ks[kb*16 + l15][d*32 + l4*8]);
                sc[kb] = __builtin_amdgcn_mfma_f32_16x16x32_bf16(qf[d], kf, sc[kb], 0, 0, 0);
            }

        // online softmax (row-reduce across 16-lane group)
        float ps[2][4], alpha[4];
        #pragma unroll
        for (int r = 0; r < 4; ++r) {
            float v = fmaxf(sc[0][r], sc[1][r])*scale;
            v = fmaxf(v, __shfl_xor(v, 1));
            v = fmaxf(v, __shfl_xor(v, 2));
            v = fmaxf(v, __shfl_xor(v, 4));
            v = fmaxf(v, __shfl_xor(v, 8));
            float nm = fmaxf(mrow[r], v);
            alpha[r] = __expf(mrow[r] - nm);
            mrow[r] = nm;
            float p0 = __expf(sc[0][r]*scale - nm);
            float p1 = __expf(sc[1][r]*scale - nm);
            ps[0][r] = p0; ps[1][r] = p1;
            float s = p0 + p1;
            s += __shfl_xor(s, 1);
            s += __shfl_xor(s, 2);
            s += __shfl_xor(s, 4);
            s += __shfl_xor(s, 8);
            lrow[r] = lrow[r]*alpha[r] + s;
        }

        // P -> LDS (per-wave private) to reach MFMA A-fragment layout
        #pragma unroll
        for (int kb = 0; kb < 2; ++kb)
            #pragma unroll
            for (int r = 0; r < 4; ++r)
                Ps[wid][l4*4 + r][kb*16 + l15] = (bf)ps[kb][r];

        // rescale O
        #pragma unroll
        for (int c = 0; c < 20; ++c)
            #pragma unroll
            for (int r = 0; r < 4; ++r) o[c][r] *= alpha[r];

        // O += P V  (A=P[16x32], B=Vt rows)
        bf16x8 pf = *reinterpret_cast<const bf16x8*>(&Ps[wid][l15][l4*8]);
        #pragma unroll
        for (int c = 0; c < 20; ++c) {
            bf16x8 vf = *reinterpret_cast<const bf16x8*>(&Vs[c*16 + l15][l4*8]);
            o[c] = __builtin_amdgcn_mfma_f32_16x16x32_bf16(pf, vf, o[c], 0, 0, 0);
        }
    }

    float inv[4];
    #pragma unroll
    for (int r = 0; r < 4; ++r) inv[r] = 1.f/lrow[r];
    #pragma unroll
    for (int c = 0; c < 20; ++c)
        #pragma unroll
        for (int r = 0; r < 4; ++r) {
            size_t idx = ((size_t)(b*SEQ + qw + l4*4 + r))*EMBED + h*HDIM + c*16 + l15;
            aout[idx] = (bf)(o[c][r]*inv[r]);
        }
}

// ---------------- launch ----------------
extern "C" void kernel_launch(void* const* d_in, const int* in_sizes, int n_in,
                              void* d_out, int out_size, void* d_ws, size_t ws_size,
                              hipStream_t stream) {
    const float* x    = (const float*)d_in[0];
    const float* Wqkv = (const float*)d_in[1];
    const float* bqkv = (const float*)d_in[2];
    const float* Wout = (const float*)d_in[3];
    const float* bout = (const float*)d_in[4];
    float* out = (float*)d_out;

    char* ws = (char*)d_ws;
    bf* xb    = (bf*)(ws);                         // 20,971,520 B
    bf* wqkvb = (bf*)(ws + 20971520);              // 39,321,600 B
    bf* woutb = (bf*)(ws + 60293120);              // 13,107,200 B
    bf* qkvb  = (bf*)(ws + 73400320);              // 62,914,560 B
    bf* vtb   = (bf*)(ws + 136314880);             // 20,971,520 B -> total 157,286,400
    bf* attnb = xb;                                // alias: x consumed by gemm1

    cvt_bf16<<<5120, 256, 0, stream>>>(x,    xb,    MTOT*EMBED);
    cvt_bf16<<<9600, 256, 0, stream>>>(Wqkv, wqkvb, FTOT*EMBED);
    cvt_bf16<<<3200, 256, 0, stream>>>(Wout, woutb, EMBED*EMBED);

    gemm_bt<true ><<<dim3(FTOT/128,  MTOT/128), 256, 0, stream>>>(xb, wqkvb, bqkv, qkvb, MTOT, FTOT, EMBED);
    repack_vt<<<dim3(SEQ/64, HDIM/64, BATCH*HEADS), 256, 0, stream>>>(qkvb, vtb);
    attn_fwd<<<dim3(SEQ/128, BATCH*HEADS), 512, 0, stream>>>(qkvb, vtb, attnb);
    gemm_bt<false><<<dim3(EMBED/128, MTOT/128), 256, 0, stream>>>(attnb, woutb, bout, out, MTOT, EMBED, EMBED);
}